// Round 1
// baseline (496.556 us; speedup 1.0000x reference)
//
#include <hip/hip_runtime.h>
#include <stdint.h>

#define T_SEQ 2048
#define NH 16
#define HD 128
#define CC 2048
#define N3 6144
#define MM 4096   // B*T

typedef short bf16x8 __attribute__((ext_vector_type(8)));
typedef float f32x4 __attribute__((ext_vector_type(4)));

__device__ __forceinline__ unsigned short f2bf(float f) {
  unsigned int u = __float_as_uint(f);
  u += 0x7FFF + ((u >> 16) & 1);   // RNE
  return (unsigned short)(u >> 16);
}
__device__ __forceinline__ float bf2f(unsigned short h) {
  return __uint_as_float(((unsigned int)h) << 16);
}

// ---------------- transpose + fp32->bf16 convert: out[n][k] = in[k][n] ----------------
__global__ __launch_bounds__(256) void k_transpose_cvt(const float* __restrict__ in,
                                                       unsigned short* __restrict__ out,
                                                       int K, int N) {
  __shared__ float tile[32][33];
  int k0 = blockIdx.x * 32;
  int n0 = blockIdx.y * 32;
  int tx = threadIdx.x & 31, ty = threadIdx.x >> 5;   // ty 0..7
  #pragma unroll
  for (int r = ty; r < 32; r += 8)
    tile[r][tx] = in[(size_t)(k0 + r) * N + n0 + tx];
  __syncthreads();
  #pragma unroll
  for (int r = ty; r < 32; r += 8)
    out[(size_t)(n0 + r) * K + k0 + tx] = f2bf(tile[tx][r]);
}

// ---------------- fp32 -> bf16 elementwise (x) ----------------
__global__ __launch_bounds__(256) void k_cvt(const float* __restrict__ in,
                                             unsigned short* __restrict__ out, int n4) {
  int i = blockIdx.x * 256 + threadIdx.x;
  if (i >= n4) return;
  float4 v = ((const float4*)in)[i];
  ushort4 o;
  o.x = f2bf(v.x); o.y = f2bf(v.y); o.z = f2bf(v.z); o.w = f2bf(v.w);
  ((ushort4*)out)[i] = o;
}

// ---------------- bf16 GEMM, m97 structure: C[M,N] = A[M,K] * Bt[N,K]^T ----------------
// EPI==0: write fp32 C.  EPI==1: scatter bf16 into q/k/v (B,H,T,D) layouts.
template<int EPI>
__global__ __launch_bounds__(256) void k_gemm(const unsigned short* __restrict__ A,
                                              const unsigned short* __restrict__ Bt,
                                              float* __restrict__ C,
                                              unsigned short* __restrict__ qo,
                                              unsigned short* __restrict__ ko,
                                              unsigned short* __restrict__ vo,
                                              int M, int N, int K) {
  __shared__ __align__(16) unsigned short As[128 * 32];
  __shared__ __align__(16) unsigned short Bs[128 * 32];
  const int tid = threadIdx.x;
  const int wave = tid >> 6, lane = tid & 63;
  const int lr = lane & 15, lg = lane >> 4;
  const int m0 = blockIdx.x * 128, n0 = blockIdx.y * 128;
  const int wm = (wave >> 1) * 64, wn = (wave & 1) * 64;
  const f32x4 fzero = {0.f, 0.f, 0.f, 0.f};
  f32x4 acc[4][4];
  #pragma unroll
  for (int a = 0; a < 4; ++a)
    #pragma unroll
    for (int b = 0; b < 4; ++b) acc[a][b] = fzero;

  for (int k0 = 0; k0 < K; k0 += 32) {
    __syncthreads();
    #pragma unroll
    for (int it = 0; it < 2; ++it) {
      int c = it * 256 + wave * 64 + lane;
      int row = c >> 2, koff = (c & 3) * 8;
      int ldsoff = (it * 256 + wave * 64) * 16;   // wave-uniform base, lane*16 added by HW
      __builtin_amdgcn_global_load_lds(
          (const __attribute__((address_space(1))) void*)(A + (size_t)(m0 + row) * K + k0 + koff),
          (__attribute__((address_space(3))) void*)((char*)As + ldsoff), 16, 0, 0);
      __builtin_amdgcn_global_load_lds(
          (const __attribute__((address_space(1))) void*)(Bt + (size_t)(n0 + row) * K + k0 + koff),
          (__attribute__((address_space(3))) void*)((char*)Bs + ldsoff), 16, 0, 0);
    }
    __syncthreads();
    bf16x8 af[4], bfr[4];
    #pragma unroll
    for (int mr = 0; mr < 4; ++mr)
      af[mr] = *(const bf16x8*)(As + (wm + mr * 16 + lr) * 32 + lg * 8);
    #pragma unroll
    for (int nr = 0; nr < 4; ++nr)
      bfr[nr] = *(const bf16x8*)(Bs + (wn + nr * 16 + lr) * 32 + lg * 8);
    #pragma unroll
    for (int mr = 0; mr < 4; ++mr)
      #pragma unroll
      for (int nr = 0; nr < 4; ++nr)
        acc[mr][nr] = __builtin_amdgcn_mfma_f32_16x16x32_bf16(af[mr], bfr[nr], acc[mr][nr], 0, 0, 0);
  }

  #pragma unroll
  for (int mr = 0; mr < 4; ++mr) {
    #pragma unroll
    for (int nr = 0; nr < 4; ++nr) {
      #pragma unroll
      for (int j = 0; j < 4; ++j) {
        int m = m0 + wm + mr * 16 + lg * 4 + j;
        int n = n0 + wn + nr * 16 + lr;
        float val = acc[mr][nr][j];
        if (EPI == 0) {
          C[(size_t)m * N + n] = val;
        } else {
          int which = n >> 11, cc = n & 2047;
          int h = cc >> 7, d = cc & 127;
          int b = m >> 11, t = m & 2047;
          unsigned short* dst = which == 0 ? qo : (which == 1 ? ko : vo);
          dst[(((size_t)(b * NH + h)) * T_SEQ + t) * HD + d] = f2bf(val);
        }
      }
    }
  }
}

// ---------------- RoPE in place on q (scaled by 1/sqrt(D)) and k ----------------
__global__ __launch_bounds__(256) void k_rope(unsigned short* __restrict__ q,
                                              unsigned short* __restrict__ k) {
  int i = blockIdx.x * 256 + threadIdx.x;   // over 32 * 2048 * 64
  int d = i & 63;
  int t = (i >> 6) & (T_SEQ - 1);
  int bh = i >> 17;
  float invf = exp2f((float)(-2 * d) * (13.287712379549449f / 128.f)); // 10000^(-2d/128)
  float ang = (float)t * invf;
  float c = cosf(ang), s = sinf(ang);
  size_t base = ((size_t)bh * T_SEQ + t) * HD + d;
  const float scale = 0.08838834764831845f;  // 1/sqrt(128)
  float q1 = bf2f(q[base]), q2 = bf2f(q[base + 64]);
  q[base]      = f2bf((q1 * c - q2 * s) * scale);
  q[base + 64] = f2bf((q2 * c + q1 * s) * scale);
  float k1 = bf2f(k[base]), k2 = bf2f(k[base + 64]);
  k[base]      = f2bf(k1 * c - k2 * s);
  k[base + 64] = f2bf(k2 * c + k1 * s);
}

// ---------------- bf16 transpose per (b,h): (T,D) -> (D,T) ----------------
__global__ __launch_bounds__(256) void k_transpose_v(const unsigned short* __restrict__ in,
                                                     unsigned short* __restrict__ out) {
  __shared__ unsigned short tile[32][33];
  int bh = blockIdx.z;
  int t0 = blockIdx.x * 32, d0 = blockIdx.y * 32;
  int tx = threadIdx.x & 31, ty = threadIdx.x >> 5;
  const unsigned short* src = in + (size_t)bh * T_SEQ * HD;
  unsigned short* dst = out + (size_t)bh * HD * T_SEQ;
  #pragma unroll
  for (int r = ty; r < 32; r += 8)
    tile[r][tx] = src[(size_t)(t0 + r) * HD + d0 + tx];
  __syncthreads();
  #pragma unroll
  for (int r = ty; r < 32; r += 8)
    dst[(size_t)(d0 + r) * T_SEQ + t0 + tx] = tile[tx][r];
}

// ---------------- causal flash attention ----------------
// Q,K: (B*H, T, D) bf16 (q pre-scaled).  Vt: (B*H, D, T) bf16.  Y: (B, T, C) bf16.
__global__ __launch_bounds__(256) void k_attn(const unsigned short* __restrict__ Q,
                                              const unsigned short* __restrict__ K,
                                              const unsigned short* __restrict__ Vt,
                                              unsigned short* __restrict__ Y) {
  __shared__ __align__(16) unsigned short Ks[64 * 128];   // XOR-swizzled
  __shared__ __align__(16) unsigned short Vs[128 * 64];   // XOR-swizzled
  __shared__ __align__(16) unsigned short Ps[64 * 80];    // padded rows (160B)
  const int qt = blockIdx.x;        // Q tile (64 rows)
  const int bh = blockIdx.y;        // 0..31
  const int b = bh >> 4, h = bh & 15;
  const int tid = threadIdx.x, wave = tid >> 6, lane = tid & 63;
  const int lr = lane & 15, lg = lane >> 4;
  const int q0 = qt * 64;
  const unsigned short* Qb = Q + (size_t)bh * T_SEQ * HD;
  const unsigned short* Kb = K + (size_t)bh * T_SEQ * HD;
  const unsigned short* Vb = Vt + (size_t)bh * HD * T_SEQ;

  // hoist Q fragments: wave's 16 rows, 4 K-slices of 32
  bf16x8 qf[4];
  #pragma unroll
  for (int kk = 0; kk < 4; ++kk)
    qf[kk] = *(const bf16x8*)(Qb + (size_t)(q0 + wave * 16 + lr) * HD + kk * 32 + lg * 8);

  const f32x4 fzero = {0.f, 0.f, 0.f, 0.f};
  f32x4 oacc[8];
  #pragma unroll
  for (int nd = 0; nd < 8; ++nd) oacc[nd] = fzero;
  float mrow[4], lrow[4];
  #pragma unroll
  for (int j = 0; j < 4; ++j) { mrow[j] = -1e30f; lrow[j] = 0.f; }

  for (int jt = 0; jt <= qt; ++jt) {
    const int tk0 = jt * 64;
    __syncthreads();
    // stage K (64x128) and V^T (128x64), both 16KB, XOR-swizzled
    #pragma unroll
    for (int it = 0; it < 4; ++it) {
      int c = it * 256 + tid;
      int rk = c >> 4, okf = (c & 15) * 8;
      bf16x8 vK = *(const bf16x8*)(Kb + (size_t)(tk0 + rk) * HD + okf);
      int bk = (rk * 256 + (c & 15) * 16) ^ ((rk & 7) << 4);
      *(bf16x8*)((char*)Ks + bk) = vK;
      int rv = c >> 3, ovf = (c & 7) * 8;
      bf16x8 vV = *(const bf16x8*)(Vb + (size_t)rv * T_SEQ + tk0 + ovf);
      int bv = (rv * 128 + (c & 7) * 16) ^ ((rv & 7) << 4);
      *(bf16x8*)((char*)Vs + bv) = vV;
    }
    __syncthreads();

    // S = Q K^T  (each wave: its 16 rows x 64 cols)
    f32x4 sacc[4];
    #pragma unroll
    for (int nr = 0; nr < 4; ++nr) sacc[nr] = fzero;
    #pragma unroll
    for (int nr = 0; nr < 4; ++nr) {
      #pragma unroll
      for (int kk = 0; kk < 4; ++kk) {
        int row = nr * 16 + lr;
        int byte = (row * 256 + kk * 64 + lg * 16) ^ ((row & 7) << 4);
        bf16x8 kf = *(const bf16x8*)((char*)Ks + byte);
        sacc[nr] = __builtin_amdgcn_mfma_f32_16x16x32_bf16(qf[kk], kf, sacc[nr], 0, 0, 0);
      }
    }

    if (jt == qt) {  // causal mask on diagonal tile
      #pragma unroll
      for (int nr = 0; nr < 4; ++nr)
        #pragma unroll
        for (int j = 0; j < 4; ++j) {
          int qg = q0 + wave * 16 + lg * 4 + j;
          int cg = tk0 + nr * 16 + lr;
          if (cg > qg) sacc[nr][j] = -1e30f;
        }
    }

    // online softmax (rows distributed: row = lg*4+j, 16 lanes share a row)
    float oscale[4];
    #pragma unroll
    for (int j = 0; j < 4; ++j) {
      float tmax = fmaxf(fmaxf(sacc[0][j], sacc[1][j]), fmaxf(sacc[2][j], sacc[3][j]));
      #pragma unroll
      for (int m = 1; m <= 8; m <<= 1) tmax = fmaxf(tmax, __shfl_xor(tmax, m));
      float mnew = fmaxf(mrow[j], tmax);
      oscale[j] = __expf(mrow[j] - mnew);
      float rsum = 0.f;
      #pragma unroll
      for (int nr = 0; nr < 4; ++nr) {
        float p = __expf(sacc[nr][j] - mnew);
        Ps[(wave * 16 + lg * 4 + j) * 80 + nr * 16 + lr] = f2bf(p);
        rsum += p;
      }
      #pragma unroll
      for (int m = 1; m <= 8; m <<= 1) rsum += __shfl_xor(rsum, m);
      lrow[j] = lrow[j] * oscale[j] + rsum;
      mrow[j] = mnew;
    }
    #pragma unroll
    for (int nd = 0; nd < 8; ++nd)
      #pragma unroll
      for (int j = 0; j < 4; ++j) oacc[nd][j] *= oscale[j];

    // PV: O += P * V   (P rows are wave-local in LDS; DS ops are in-order per wave)
    bf16x8 pf[2];
    #pragma unroll
    for (int kk = 0; kk < 2; ++kk)
      pf[kk] = *(const bf16x8*)(Ps + (wave * 16 + lr) * 80 + kk * 32 + lg * 8);
    #pragma unroll
    for (int nd = 0; nd < 8; ++nd) {
      #pragma unroll
      for (int kk = 0; kk < 2; ++kk) {
        int row = nd * 16 + lr;
        int byte = (row * 128 + kk * 64 + lg * 16) ^ ((row & 7) << 4);
        bf16x8 vf = *(const bf16x8*)((char*)Vs + byte);
        oacc[nd] = __builtin_amdgcn_mfma_f32_16x16x32_bf16(pf[kk], vf, oacc[nd], 0, 0, 0);
      }
    }
  }

  // epilogue: O / l -> Y (B,T,C)
  #pragma unroll
  for (int j = 0; j < 4; ++j) {
    float inv = 1.f / lrow[j];
    int qg = q0 + wave * 16 + lg * 4 + j;
    size_t base = ((size_t)b * T_SEQ + qg) * CC + h * HD;
    #pragma unroll
    for (int nd = 0; nd < 8; ++nd)
      Y[base + nd * 16 + lr] = f2bf(oacc[nd][j] * inv);
  }
}

extern "C" void kernel_launch(void* const* d_in, const int* in_sizes, int n_in,
                              void* d_out, int out_size, void* d_ws, size_t ws_size,
                              hipStream_t stream) {
  const float* x     = (const float*)d_in[0];
  const float* Wqkv  = (const float*)d_in[1];
  const float* Wproj = (const float*)d_in[2];
  float* out = (float*)d_out;
  char* ws = (char*)d_ws;
  const size_t MB = 1024 * 1024;
  unsigned short* WqkvT  = (unsigned short*)(ws + 0);        // 24MB; dead after GEMM1
  unsigned short* vt     = (unsigned short*)(ws + 0);        // 16MB, aliases WqkvT
  unsigned short* WprojT = (unsigned short*)(ws + 24 * MB);  // 8MB
  unsigned short* xb     = (unsigned short*)(ws + 32 * MB);  // 16MB; dead after GEMM1
  unsigned short* y      = xb;                               // aliases xb
  unsigned short* q      = (unsigned short*)(ws + 48 * MB);  // 16MB
  unsigned short* k      = (unsigned short*)(ws + 64 * MB);  // 16MB
  unsigned short* v      = (unsigned short*)(ws + 80 * MB);  // 16MB  (total 96MB)

  k_transpose_cvt<<<dim3(CC / 32, N3 / 32), 256, 0, stream>>>(Wqkv, WqkvT, CC, N3);
  k_transpose_cvt<<<dim3(CC / 32, CC / 32), 256, 0, stream>>>(Wproj, WprojT, CC, CC);
  k_cvt<<<(MM * CC / 4) / 256, 256, 0, stream>>>(x, xb, MM * CC / 4);
  k_gemm<1><<<dim3(MM / 128, N3 / 128), 256, 0, stream>>>(xb, WqkvT, nullptr, q, k, v, MM, N3, CC);
  k_rope<<<(32 * T_SEQ * 64) / 256, 256, 0, stream>>>(q, k);
  k_transpose_v<<<dim3(T_SEQ / 32, HD / 32, 32), 256, 0, stream>>>(v, vt);
  k_attn<<<dim3(T_SEQ / 64, 32), 256, 0, stream>>>(q, k, vt, y);
  k_gemm<0><<<dim3(MM / 128, CC / 128), 256, 0, stream>>>(y, WprojT, out, nullptr, nullptr, nullptr, MM, CC, CC);
}

// Round 2
// 336.832 us; speedup vs baseline: 1.4742x; 1.4742x over previous
//
#include <hip/hip_runtime.h>
#include <stdint.h>

#define T_SEQ 2048
#define NH 16
#define HD 128
#define CC 2048
#define N3 6144
#define MM 4096   // B*T

typedef short bf16x8 __attribute__((ext_vector_type(8)));
typedef float f32x4 __attribute__((ext_vector_type(4)));

__device__ __forceinline__ unsigned short f2bf(float f) {
  unsigned int u = __float_as_uint(f);
  u += 0x7FFF + ((u >> 16) & 1);   // RNE
  return (unsigned short)(u >> 16);
}
__device__ __forceinline__ float bf2f(unsigned short h) {
  return __uint_as_float(((unsigned int)h) << 16);
}

// ---------------- transpose + fp32->bf16 convert: out[n][k] = in[k][n] ----------------
__global__ __launch_bounds__(256) void k_transpose_cvt(const float* __restrict__ in,
                                                       unsigned short* __restrict__ out,
                                                       int K, int N) {
  __shared__ float tile[32][33];
  int k0 = blockIdx.x * 32;
  int n0 = blockIdx.y * 32;
  int tx = threadIdx.x & 31, ty = threadIdx.x >> 5;   // ty 0..7
  #pragma unroll
  for (int r = ty; r < 32; r += 8)
    tile[r][tx] = in[(size_t)(k0 + r) * N + n0 + tx];
  __syncthreads();
  #pragma unroll
  for (int r = ty; r < 32; r += 8)
    out[(size_t)(n0 + r) * K + k0 + tx] = f2bf(tile[tx][r]);
}

// ---------------- fp32 -> bf16 elementwise (x) ----------------
__global__ __launch_bounds__(256) void k_cvt(const float* __restrict__ in,
                                             unsigned short* __restrict__ out, int n4) {
  int i = blockIdx.x * 256 + threadIdx.x;
  if (i >= n4) return;
  float4 v = ((const float4*)in)[i];
  ushort4 o;
  o.x = f2bf(v.x); o.y = f2bf(v.y); o.z = f2bf(v.z); o.w = f2bf(v.w);
  ((ushort4*)out)[i] = o;
}

// ---------------- bf16 GEMM, m97 structure: C[M,N] = A[M,K] * Bt[N,K]^T ----------------
// EPI==0: write fp32 C.  EPI==1: scatter bf16 into q/k/v (B,H,T,D) layouts.
template<int EPI>
__global__ __launch_bounds__(256) void k_gemm(const unsigned short* __restrict__ A,
                                              const unsigned short* __restrict__ Bt,
                                              float* __restrict__ C,
                                              unsigned short* __restrict__ qo,
                                              unsigned short* __restrict__ ko,
                                              unsigned short* __restrict__ vo,
                                              int M, int N, int K) {
  __shared__ __align__(16) unsigned short As[128 * 32];
  __shared__ __align__(16) unsigned short Bs[128 * 32];
  const int tid = threadIdx.x;
  const int wave = tid >> 6, lane = tid & 63;
  const int lr = lane & 15, lg = lane >> 4;
  const int m0 = blockIdx.x * 128, n0 = blockIdx.y * 128;
  const int wm = (wave >> 1) * 64, wn = (wave & 1) * 64;
  const f32x4 fzero = {0.f, 0.f, 0.f, 0.f};
  f32x4 acc[4][4];
  #pragma unroll
  for (int a = 0; a < 4; ++a)
    #pragma unroll
    for (int b = 0; b < 4; ++b) acc[a][b] = fzero;

  for (int k0 = 0; k0 < K; k0 += 32) {
    __syncthreads();
    #pragma unroll
    for (int it = 0; it < 2; ++it) {
      int c = it * 256 + wave * 64 + lane;
      int row = c >> 2, koff = (c & 3) * 8;
      int ldsoff = (it * 256 + wave * 64) * 16;   // wave-uniform base, lane*16 added by HW
      __builtin_amdgcn_global_load_lds(
          (const __attribute__((address_space(1))) void*)(A + (size_t)(m0 + row) * K + k0 + koff),
          (__attribute__((address_space(3))) void*)((char*)As + ldsoff), 16, 0, 0);
      __builtin_amdgcn_global_load_lds(
          (const __attribute__((address_space(1))) void*)(Bt + (size_t)(n0 + row) * K + k0 + koff),
          (__attribute__((address_space(3))) void*)((char*)Bs + ldsoff), 16, 0, 0);
    }
    __syncthreads();
    bf16x8 af[4], bfr[4];
    #pragma unroll
    for (int mr = 0; mr < 4; ++mr)
      af[mr] = *(const bf16x8*)(As + (wm + mr * 16 + lr) * 32 + lg * 8);
    #pragma unroll
    for (int nr = 0; nr < 4; ++nr)
      bfr[nr] = *(const bf16x8*)(Bs + (wn + nr * 16 + lr) * 32 + lg * 8);
    #pragma unroll
    for (int mr = 0; mr < 4; ++mr)
      #pragma unroll
      for (int nr = 0; nr < 4; ++nr)
        acc[mr][nr] = __builtin_amdgcn_mfma_f32_16x16x32_bf16(af[mr], bfr[nr], acc[mr][nr], 0, 0, 0);
  }

  #pragma unroll
  for (int mr = 0; mr < 4; ++mr) {
    #pragma unroll
    for (int nr = 0; nr < 4; ++nr) {
      #pragma unroll
      for (int j = 0; j < 4; ++j) {
        int m = m0 + wm + mr * 16 + lg * 4 + j;
        int n = n0 + wn + nr * 16 + lr;
        float val = acc[mr][nr][j];
        if (EPI == 0) {
          C[(size_t)m * N + n] = val;
        } else {
          int which = n >> 11, cc = n & 2047;
          int h = cc >> 7, d = cc & 127;
          int b = m >> 11, t = m & 2047;
          unsigned short* dst = which == 0 ? qo : (which == 1 ? ko : vo);
          dst[(((size_t)(b * NH + h)) * T_SEQ + t) * HD + d] = f2bf(val);
        }
      }
    }
  }
}

// ---------------- RoPE in place on q (scaled by 1/sqrt(D)) and k ----------------
__global__ __launch_bounds__(256) void k_rope(unsigned short* __restrict__ q,
                                              unsigned short* __restrict__ k) {
  int i = blockIdx.x * 256 + threadIdx.x;   // over 32 * 2048 * 64
  int d = i & 63;
  int t = (i >> 6) & (T_SEQ - 1);
  int bh = i >> 17;
  float invf = exp2f((float)(-2 * d) * (13.287712379549449f / 128.f)); // 10000^(-2d/128)
  float ang = (float)t * invf;
  float c = cosf(ang), s = sinf(ang);
  size_t base = ((size_t)bh * T_SEQ + t) * HD + d;
  const float scale = 0.08838834764831845f;  // 1/sqrt(128)
  float q1 = bf2f(q[base]), q2 = bf2f(q[base + 64]);
  q[base]      = f2bf((q1 * c - q2 * s) * scale);
  q[base + 64] = f2bf((q2 * c + q1 * s) * scale);
  float k1 = bf2f(k[base]), k2 = bf2f(k[base + 64]);
  k[base]      = f2bf(k1 * c - k2 * s);
  k[base + 64] = f2bf(k2 * c + k1 * s);
}

// ---------------- bf16 transpose per (b,h): (T,D) -> (D,T) ----------------
__global__ __launch_bounds__(256) void k_transpose_v(const unsigned short* __restrict__ in,
                                                     unsigned short* __restrict__ out) {
  __shared__ unsigned short tile[32][33];
  int bh = blockIdx.z;
  int t0 = blockIdx.x * 32, d0 = blockIdx.y * 32;
  int tx = threadIdx.x & 31, ty = threadIdx.x >> 5;
  const unsigned short* src = in + (size_t)bh * T_SEQ * HD;
  unsigned short* dst = out + (size_t)bh * HD * T_SEQ;
  #pragma unroll
  for (int r = ty; r < 32; r += 8)
    tile[r][tx] = src[(size_t)(t0 + r) * HD + d0 + tx];
  __syncthreads();
  #pragma unroll
  for (int r = ty; r < 32; r += 8)
    dst[(size_t)(d0 + r) * T_SEQ + t0 + tx] = tile[tx][r];
}

// ---------------- causal flash attention (LPT order + reg-prefetch pipeline) ----------------
// Q,K: (B*H, T, D) bf16 (q pre-scaled).  Vt: (B*H, D, T) bf16.  Y: (B, T, C) bf16.
__global__ __launch_bounds__(256) void k_attn(const unsigned short* __restrict__ Q,
                                              const unsigned short* __restrict__ K,
                                              const unsigned short* __restrict__ Vt,
                                              unsigned short* __restrict__ Y) {
  __shared__ __align__(16) unsigned short Ks[64 * 128];   // XOR-swizzled
  __shared__ __align__(16) unsigned short Vs[128 * 64];   // XOR-swizzled
  __shared__ __align__(16) unsigned short Ps[64 * 80];    // padded rows (160B)
  const int bh = blockIdx.x;                    // fast dim: heads spread over XCDs
  const int qt = (T_SEQ / 64 - 1) - blockIdx.y; // heavy Q-tiles dispatch first (LPT)
  const int b = bh >> 4, h = bh & 15;
  const int tid = threadIdx.x, wave = tid >> 6, lane = tid & 63;
  const int lr = lane & 15, lg = lane >> 4;
  const int q0 = qt * 64;
  const unsigned short* Qb = Q + (size_t)bh * T_SEQ * HD;
  const unsigned short* Kb = K + (size_t)bh * T_SEQ * HD;
  const unsigned short* Vb = Vt + (size_t)bh * HD * T_SEQ;

  // per-thread staging geometry (constant across iterations)
  int rkA[4], okA[4], rvA[4], ovA[4], bkA[4], bvA[4];
  #pragma unroll
  for (int it = 0; it < 4; ++it) {
    int c = it * 256 + tid;
    rkA[it] = c >> 4; okA[it] = (c & 15) * 8;
    bkA[it] = (rkA[it] * 256 + (c & 15) * 16) ^ ((rkA[it] & 7) << 4);
    rvA[it] = c >> 3; ovA[it] = (c & 7) * 8;
    bvA[it] = (rvA[it] * 128 + (c & 7) * 16) ^ ((rvA[it] & 7) << 4);
  }

  // hoist Q fragments: wave's 16 rows, 4 K-slices of 32
  bf16x8 qf[4];
  #pragma unroll
  for (int kk = 0; kk < 4; ++kk)
    qf[kk] = *(const bf16x8*)(Qb + (size_t)(q0 + wave * 16 + lr) * HD + kk * 32 + lg * 8);

  const f32x4 fzero = {0.f, 0.f, 0.f, 0.f};
  f32x4 oacc[8];
  #pragma unroll
  for (int nd = 0; nd < 8; ++nd) oacc[nd] = fzero;
  float mrow[4], lrow[4];
  #pragma unroll
  for (int j = 0; j < 4; ++j) { mrow[j] = -1e30f; lrow[j] = 0.f; }

  // prologue: prefetch tile 0 into registers
  bf16x8 kst[4], vst[4];
  #pragma unroll
  for (int it = 0; it < 4; ++it) {
    kst[it] = *(const bf16x8*)(Kb + (size_t)rkA[it] * HD + okA[it]);
    vst[it] = *(const bf16x8*)(Vb + (size_t)rvA[it] * T_SEQ + ovA[it]);
  }

  for (int jt = 0; jt <= qt; ++jt) {
    const int tk0 = jt * 64;
    __syncthreads();   // previous iteration's LDS reads done
    // write staged regs -> LDS (swizzled)
    #pragma unroll
    for (int it = 0; it < 4; ++it) {
      *(bf16x8*)((char*)Ks + bkA[it]) = kst[it];
      *(bf16x8*)((char*)Vs + bvA[it]) = vst[it];
    }
    // issue next tile's loads; they fly under this tile's compute
    if (jt < qt) {
      const int nk0 = tk0 + 64;
      #pragma unroll
      for (int it = 0; it < 4; ++it) {
        kst[it] = *(const bf16x8*)(Kb + (size_t)(nk0 + rkA[it]) * HD + okA[it]);
        vst[it] = *(const bf16x8*)(Vb + (size_t)rvA[it] * T_SEQ + nk0 + ovA[it]);
      }
    }
    __syncthreads();   // LDS tile ready

    // S = Q K^T  (each wave: its 16 rows x 64 cols)
    f32x4 sacc[4];
    #pragma unroll
    for (int nr = 0; nr < 4; ++nr) sacc[nr] = fzero;
    #pragma unroll
    for (int nr = 0; nr < 4; ++nr) {
      #pragma unroll
      for (int kk = 0; kk < 4; ++kk) {
        int row = nr * 16 + lr;
        int byte = (row * 256 + kk * 64 + lg * 16) ^ ((row & 7) << 4);
        bf16x8 kf = *(const bf16x8*)((char*)Ks + byte);
        sacc[nr] = __builtin_amdgcn_mfma_f32_16x16x32_bf16(qf[kk], kf, sacc[nr], 0, 0, 0);
      }
    }

    if (jt == qt) {  // causal mask on diagonal tile
      #pragma unroll
      for (int nr = 0; nr < 4; ++nr)
        #pragma unroll
        for (int j = 0; j < 4; ++j) {
          int qg = q0 + wave * 16 + lg * 4 + j;
          int cg = tk0 + nr * 16 + lr;
          if (cg > qg) sacc[nr][j] = -1e30f;
        }
    }

    // online softmax (rows distributed: row = lg*4+j, 16 lanes share a row)
    float oscale[4];
    #pragma unroll
    for (int j = 0; j < 4; ++j) {
      float tmax = fmaxf(fmaxf(sacc[0][j], sacc[1][j]), fmaxf(sacc[2][j], sacc[3][j]));
      #pragma unroll
      for (int m = 1; m <= 8; m <<= 1) tmax = fmaxf(tmax, __shfl_xor(tmax, m));
      float mnew = fmaxf(mrow[j], tmax);
      oscale[j] = __expf(mrow[j] - mnew);
      float rsum = 0.f;
      #pragma unroll
      for (int nr = 0; nr < 4; ++nr) {
        float p = __expf(sacc[nr][j] - mnew);
        Ps[(wave * 16 + lg * 4 + j) * 80 + nr * 16 + lr] = f2bf(p);
        rsum += p;
      }
      #pragma unroll
      for (int m = 1; m <= 8; m <<= 1) rsum += __shfl_xor(rsum, m);
      lrow[j] = lrow[j] * oscale[j] + rsum;
      mrow[j] = mnew;
    }
    #pragma unroll
    for (int nd = 0; nd < 8; ++nd)
      #pragma unroll
      for (int j = 0; j < 4; ++j) oacc[nd][j] *= oscale[j];

    // PV: O += P * V   (P rows are wave-local in LDS; DS ops are in-order per wave)
    bf16x8 pf[2];
    #pragma unroll
    for (int kk = 0; kk < 2; ++kk)
      pf[kk] = *(const bf16x8*)(Ps + (wave * 16 + lr) * 80 + kk * 32 + lg * 8);
    #pragma unroll
    for (int nd = 0; nd < 8; ++nd) {
      #pragma unroll
      for (int kk = 0; kk < 2; ++kk) {
        int row = nd * 16 + lr;
        int byte = (row * 128 + kk * 64 + lg * 16) ^ ((row & 7) << 4);
        bf16x8 vf = *(const bf16x8*)((char*)Vs + byte);
        oacc[nd] = __builtin_amdgcn_mfma_f32_16x16x32_bf16(pf[kk], vf, oacc[nd], 0, 0, 0);
      }
    }
  }

  // epilogue: O / l -> Y (B,T,C)
  #pragma unroll
  for (int j = 0; j < 4; ++j) {
    float inv = 1.f / lrow[j];
    int qg = q0 + wave * 16 + lg * 4 + j;
    size_t base = ((size_t)b * T_SEQ + qg) * CC + h * HD;
    #pragma unroll
    for (int nd = 0; nd < 8; ++nd)
      Y[base + nd * 16 + lr] = f2bf(oacc[nd][j] * inv);
  }
}

extern "C" void kernel_launch(void* const* d_in, const int* in_sizes, int n_in,
                              void* d_out, int out_size, void* d_ws, size_t ws_size,
                              hipStream_t stream) {
  const float* x     = (const float*)d_in[0];
  const float* Wqkv  = (const float*)d_in[1];
  const float* Wproj = (const float*)d_in[2];
  float* out = (float*)d_out;
  char* ws = (char*)d_ws;
  const size_t MB = 1024 * 1024;
  unsigned short* WqkvT  = (unsigned short*)(ws + 0);        // 24MB; dead after GEMM1
  unsigned short* vt     = (unsigned short*)(ws + 0);        // 16MB, aliases WqkvT
  unsigned short* WprojT = (unsigned short*)(ws + 24 * MB);  // 8MB
  unsigned short* xb     = (unsigned short*)(ws + 32 * MB);  // 16MB; dead after GEMM1
  unsigned short* y      = xb;                               // aliases xb
  unsigned short* q      = (unsigned short*)(ws + 48 * MB);  // 16MB
  unsigned short* k      = (unsigned short*)(ws + 64 * MB);  // 16MB
  unsigned short* v      = (unsigned short*)(ws + 80 * MB);  // 16MB  (total 96MB)

  k_transpose_cvt<<<dim3(CC / 32, N3 / 32), 256, 0, stream>>>(Wqkv, WqkvT, CC, N3);
  k_transpose_cvt<<<dim3(CC / 32, CC / 32), 256, 0, stream>>>(Wproj, WprojT, CC, CC);
  k_cvt<<<(MM * CC / 4) / 256, 256, 0, stream>>>(x, xb, MM * CC / 4);
  k_gemm<1><<<dim3(MM / 128, N3 / 128), 256, 0, stream>>>(xb, WqkvT, nullptr, q, k, v, MM, N3, CC);
  k_rope<<<(32 * T_SEQ * 64) / 256, 256, 0, stream>>>(q, k);
  k_transpose_v<<<dim3(T_SEQ / 32, HD / 32, 32), 256, 0, stream>>>(v, vt);
  k_attn<<<dim3(32, T_SEQ / 64), 256, 0, stream>>>(q, k, vt, y);
  k_gemm<0><<<dim3(MM / 128, CC / 128), 256, 0, stream>>>(y, WprojT, out, nullptr, nullptr, nullptr, MM, CC, CC);
}